// Round 1
// baseline (2370.197 us; speedup 1.0000x reference)
//
#include <hip/hip_runtime.h>
#include <stdint.h>

#define DEVI __device__ __forceinline__

typedef __attribute__((ext_vector_type(4))) float f32x4;
typedef __attribute__((ext_vector_type(8))) __bf16 bf16x8;

// ---------- bf16 helpers (RNE) ----------
DEVI unsigned short f2bf(float f) {
  union { float f; unsigned u; } x; x.f = f;
  unsigned r = x.u + 0x7fffu + ((x.u >> 16) & 1u);
  return (unsigned short)(r >> 16);
}
DEVI float bf2f(unsigned short h) {
  union { unsigned u; float f; } x; x.u = ((unsigned)h) << 16; return x.f;
}

DEVI void gload_lds16(const void* g, void* l) {
  __builtin_amdgcn_global_load_lds(
      (const __attribute__((address_space(1))) unsigned int*)g,
      (__attribute__((address_space(3))) unsigned int*)l, 16, 0, 0);
}

// ---------- kernel: out = x + pos_embed ----------
__global__ void k_addpos(const float* __restrict__ x, const float* __restrict__ pos,
                         float* __restrict__ out) {
  int i = blockIdx.x * 256 + threadIdx.x;           // float4 index, total 1M
  const int NC4 = 1024 * 1024 / 4;                  // N*C in float4
  f32x4 a = ((const f32x4*)x)[i];
  f32x4 p = ((const f32x4*)pos)[i & (NC4 - 1)];
  ((f32x4*)out)[i] = a + p;
}

// ---------- kernel: LayerNorm fp32 -> bf16, one wave per row (C=1024) ----------
__global__ __launch_bounds__(256) void k_ln(const float* __restrict__ in,
                                            const float* __restrict__ g,
                                            const float* __restrict__ b,
                                            unsigned short* __restrict__ out) {
  int wid = threadIdx.x >> 6, lane = threadIdx.x & 63;
  int row = blockIdx.x * 4 + wid;
  const float* r = in + (size_t)row * 1024;
  f32x4 v[4];
  float s = 0.f, s2 = 0.f;
#pragma unroll
  for (int j = 0; j < 4; j++) {
    v[j] = ((const f32x4*)r)[j * 64 + lane];
#pragma unroll
    for (int c = 0; c < 4; c++) { s += v[j][c]; s2 += v[j][c] * v[j][c]; }
  }
#pragma unroll
  for (int off = 32; off; off >>= 1) { s += __shfl_xor(s, off); s2 += __shfl_xor(s2, off); }
  float mean = s * (1.0f / 1024.0f);
  float var = s2 * (1.0f / 1024.0f) - mean * mean;
  float rstd = rsqrtf(var + 1e-5f);
  unsigned short* orow = out + (size_t)row * 1024;
#pragma unroll
  for (int j = 0; j < 4; j++) {
    f32x4 gv = ((const f32x4*)g)[j * 64 + lane];
    f32x4 bv = ((const f32x4*)b)[j * 64 + lane];
    float y0 = (v[j][0] - mean) * rstd * gv[0] + bv[0];
    float y1 = (v[j][1] - mean) * rstd * gv[1] + bv[1];
    float y2 = (v[j][2] - mean) * rstd * gv[2] + bv[2];
    float y3 = (v[j][3] - mean) * rstd * gv[3] + bv[3];
    uint2 w;
    w.x = (unsigned)f2bf(y0) | ((unsigned)f2bf(y1) << 16);
    w.y = (unsigned)f2bf(y2) | ((unsigned)f2bf(y3) << 16);
    *(uint2*)(orow + (j * 64 + lane) * 4) = w;
  }
}

// ---------- GEMM: C[M,Nout] = A(bf16)[M,K] @ W(fp32)[K,Nout] + bias, epilogues ----------
// EPI 0: QKV split-write (q scaled by 1/8) to [3][B,H,N,64] bf16
// EPI 1: residual add fp32 (proj)
// EPI 2: GELU -> bf16 (fc1)
// EPI 3: residual add fp32 (fc2)
template <int EPI>
__global__ __launch_bounds__(256, 3) void k_gemm(const unsigned short* __restrict__ A,
                                                 const float* __restrict__ W,
                                                 const float* __restrict__ bias,
                                                 unsigned short* __restrict__ outb,
                                                 float* __restrict__ outf,
                                                 int K, int Nout) {
  __shared__ unsigned short As[2][128 * 32];   // [row][k] linear, 8KB each
  __shared__ unsigned short Bs[2][128 * 40];   // [col][k] padded stride 40 (80B rows)
  const int tid = threadIdx.x, wid = tid >> 6, lane = tid & 63;
  const int r16 = lane & 15, gq = lane >> 4;
  const int bm = blockIdx.y, bn = blockIdx.x;
  const int row0g = bm * 128, col0g = bn * 128;

  // B staging: thread covers 4x4 block; sbk fast for bank-friendly ds_writes
  const int sbk = tid & 7, sbn = tid >> 3;
  const float* Wp = W + (size_t)(4 * sbk) * Nout + col0g + 4 * sbn;

  f32x4 breg[4];
  auto loadB = [&](int t) {
    const float* p = Wp + (size_t)t * 32 * Nout;
#pragma unroll
    for (int r = 0; r < 4; r++) breg[r] = *(const f32x4*)(p + (size_t)r * Nout);
  };
  auto stageB = [&](int buf) {
#pragma unroll
    for (int c = 0; c < 4; c++) {
      uint2 w;
      w.x = (unsigned)f2bf(breg[0][c]) | ((unsigned)f2bf(breg[1][c]) << 16);
      w.y = (unsigned)f2bf(breg[2][c]) | ((unsigned)f2bf(breg[3][c]) << 16);
      *(uint2*)&Bs[buf][(4 * sbn + c) * 40 + 4 * sbk] = w;
    }
  };
  auto stageA = [&](int buf, int t) {
#pragma unroll
    for (int p = 0; p < 2; p++) {
      int ci = p * 256 + wid * 64 + lane;
      const unsigned short* src = A + (size_t)(row0g + (ci >> 2)) * K + t * 32 + (ci & 3) * 8;
      gload_lds16(src, &As[buf][(p * 256 + wid * 64) * 8]);
    }
  };

  f32x4 acc[4][4] = {};
  const int NT = K >> 5;
  loadB(0);
  stageA(0, 0);
  int cur = 0;
  const int a_base = (wid >> 1) * 64, b_base = (wid & 1) * 64;
  for (int t = 0; t < NT; t++) {
    stageB(cur);
    __syncthreads();
    if (t + 1 < NT) { loadB(t + 1); stageA(cur ^ 1, t + 1); }
    bf16x8 af[4], bf[4];
#pragma unroll
    for (int im = 0; im < 4; im++)
      af[im] = *(const bf16x8*)&As[cur][(a_base + im * 16 + r16) * 32 + gq * 8];
#pragma unroll
    for (int in = 0; in < 4; in++)
      bf[in] = *(const bf16x8*)&Bs[cur][(b_base + in * 16 + r16) * 40 + gq * 8];
#pragma unroll
    for (int im = 0; im < 4; im++)
#pragma unroll
      for (int in = 0; in < 4; in++)
        acc[im][in] = __builtin_amdgcn_mfma_f32_16x16x32_bf16(af[im], bf[in], acc[im][in], 0, 0, 0);
    cur ^= 1;
  }

  // epilogue
  const int row0 = row0g + a_base, col0 = col0g + b_base;
#pragma unroll
  for (int in = 0; in < 4; in++) {
    int c = col0 + in * 16 + r16;
    float bv = bias[c];
#pragma unroll
    for (int im = 0; im < 4; im++) {
      int rb = row0 + im * 16 + gq * 4;
#pragma unroll
      for (int jr = 0; jr < 4; jr++) {
        float val = acc[im][in][jr] + bv;
        int r = rb + jr;
        if (EPI == 0) {
          int part = c >> 10, cc = c & 1023;
          int hh = cc >> 6, d = cc & 63;
          int bb = r >> 10, n = r & 1023;
          if (part == 0) val *= 0.125f;  // SCALE = 64^-0.5
          outb[(size_t)part * 4194304 + ((size_t)(bb * 16 + hh) * 1024 + n) * 64 + d] = f2bf(val);
        } else if (EPI == 2) {
          float gx = 0.5f * val * (1.0f + erff(val * 0.70710678118f));
          outb[(size_t)r * 4096 + c] = f2bf(gx);
        } else {
          outf[(size_t)r * 1024 + c] += val;
        }
      }
    }
  }
}

// ---------- attention: scores + row max/argmax/sum-exp + threshold gather ----------
// q pre-scaled by 1/8. Layouts: q,k,v = [B*H, N, 64] bf16. attn_out = [B, N, C] bf16.
__global__ __launch_bounds__(256) void k_attn(const unsigned short* __restrict__ q,
                                              const unsigned short* __restrict__ k,
                                              const unsigned short* __restrict__ v,
                                              unsigned short* __restrict__ ao) {
  const int wid = threadIdx.x >> 6, lane = threadIdx.x & 63;
  const int r16 = lane & 15, g = lane >> 4;
  const int bh = blockIdx.x >> 4, qt = blockIdx.x & 15;
  const int b = bh >> 4, h = bh & 15;
  const unsigned short* qb = q + (size_t)bh * 1024 * 64;
  const unsigned short* kb = k + (size_t)bh * 1024 * 64;
  const unsigned short* vb = v + (size_t)bh * 1024 * 64;
  const int n_base = qt * 64 + wid * 16;

  bf16x8 qf0 = *(const bf16x8*)(qb + (size_t)(n_base + r16) * 64 + g * 8);
  bf16x8 qf1 = *(const bf16x8*)(qb + (size_t)(n_base + r16) * 64 + 32 + g * 8);

  float gsum[4] = {0.f, 0.f, 0.f, 0.f};
  float gmax[4] = {-3e38f, -3e38f, -3e38f, -3e38f};
  int gidx[4] = {0, 0, 0, 0};

  for (int mt = 0; mt < 64; mt++) {
    int m0 = mt * 16;
    bf16x8 kf0 = *(const bf16x8*)(kb + (size_t)(m0 + r16) * 64 + g * 8);
    bf16x8 kf1 = *(const bf16x8*)(kb + (size_t)(m0 + r16) * 64 + 32 + g * 8);
    f32x4 s = {0.f, 0.f, 0.f, 0.f};
    s = __builtin_amdgcn_mfma_f32_16x16x32_bf16(qf0, kf0, s, 0, 0, 0);
    s = __builtin_amdgcn_mfma_f32_16x16x32_bf16(qf1, kf1, s, 0, 0, 0);
#pragma unroll
    for (int jr = 0; jr < 4; jr++) {
      float sc = s[jr];
      float e = __expf(sc);
#pragma unroll
      for (int off = 1; off < 16; off <<= 1) e += __shfl_xor(e, off);
      float mv = sc; int mi = m0 + r16;
#pragma unroll
      for (int off = 1; off < 16; off <<= 1) {
        float ov = __shfl_xor(mv, off);
        int oi = __shfl_xor(mi, off);
        if (ov > mv) { mv = ov; mi = oi; }
      }
      gsum[jr] += e;
      if (mv > gmax[jr]) { gmax[jr] = mv; gidx[jr] = mi; }
    }
  }

#pragma unroll
  for (int jr = 0; jr < 4; jr++) {
    int n = n_base + g * 4 + jr;
    float wgt = __expf(gmax[jr]) / gsum[jr];
    uint2 w; w.x = 0u; w.y = 0u;
    if (wgt > 0.5f) {
      uint2 raw = *(const uint2*)(vb + (size_t)gidx[jr] * 64 + r16 * 4);
      unsigned short a0 = raw.x & 0xffff, a1 = raw.x >> 16;
      unsigned short a2 = raw.y & 0xffff, a3 = raw.y >> 16;
      w.x = (unsigned)f2bf(wgt * bf2f(a0)) | ((unsigned)f2bf(wgt * bf2f(a1)) << 16);
      w.y = (unsigned)f2bf(wgt * bf2f(a2)) | ((unsigned)f2bf(wgt * bf2f(a3)) << 16);
    }
    *(uint2*)(ao + ((size_t)b * 1024 + n) * 1024 + h * 64 + r16 * 4) = w;
  }
}

// ---------- launcher ----------
extern "C" void kernel_launch(void* const* d_in, const int* in_sizes, int n_in,
                              void* d_out, int out_size, void* d_ws, size_t ws_size,
                              hipStream_t stream) {
  const float* x      = (const float*)d_in[0];
  const float* pos    = (const float*)d_in[1];
  const float* qkv_w  = (const float*)d_in[2];
  const float* qkv_b  = (const float*)d_in[3];
  const float* proj_w = (const float*)d_in[4];
  const float* proj_b = (const float*)d_in[5];
  const float* ln1_g  = (const float*)d_in[6];
  const float* ln1_b  = (const float*)d_in[7];
  const float* ln2_g  = (const float*)d_in[8];
  const float* ln2_b  = (const float*)d_in[9];
  const float* fc1_w  = (const float*)d_in[10];
  const float* fc1_b  = (const float*)d_in[11];
  const float* fc2_w  = (const float*)d_in[12];
  const float* fc2_b  = (const float*)d_in[13];
  float* out = (float*)d_out;

  char* ws = (char*)d_ws;
  unsigned short* xh  = (unsigned short*)ws;                       // 8 MB  (LN out / attn_out)
  unsigned short* qkv = (unsigned short*)(ws + (8u << 20));        // 24 MB (q,k,v each 4M elems)
  unsigned short* m1  = (unsigned short*)(ws + (32u << 20));       // 32 MB (gelu out)

  k_addpos<<<4096, 256, 0, stream>>>(x, pos, out);
  for (int l = 0; l < 4; l++) {
    k_ln<<<1024, 256, 0, stream>>>(out, ln1_g + l * 1024, ln1_b + l * 1024, xh);
    k_gemm<0><<<dim3(24, 32), 256, 0, stream>>>(xh, qkv_w + (size_t)l * 1024 * 3072,
                                                qkv_b + l * 3072, qkv, nullptr, 1024, 3072);
    k_attn<<<1024, 256, 0, stream>>>(qkv, qkv + 4194304, qkv + 2 * 4194304, xh);
    k_gemm<1><<<dim3(8, 32), 256, 0, stream>>>(xh, proj_w + (size_t)l * 1024 * 1024,
                                               proj_b + l * 1024, nullptr, out, 1024, 1024);
    k_ln<<<1024, 256, 0, stream>>>(out, ln2_g + l * 1024, ln2_b + l * 1024, xh);
    k_gemm<2><<<dim3(32, 32), 256, 0, stream>>>(xh, fc1_w + (size_t)l * 1024 * 4096,
                                                fc1_b + l * 4096, m1, nullptr, 1024, 4096);
    k_gemm<3><<<dim3(8, 32), 256, 0, stream>>>(m1, fc2_w + (size_t)l * 4096 * 1024,
                                               fc2_b + l * 1024, nullptr, out, 4096, 1024);
  }
}

// Round 2
// 1689.898 us; speedup vs baseline: 1.4026x; 1.4026x over previous
//
#include <hip/hip_runtime.h>
#include <stdint.h>

#define DEVI __device__ __forceinline__

typedef __attribute__((ext_vector_type(4))) float f32x4;
typedef __attribute__((ext_vector_type(8))) __bf16 bf16x8;

// ---------- bf16 helpers (RNE) ----------
DEVI unsigned short f2bf(float f) {
  union { float f; unsigned u; } x; x.f = f;
  unsigned r = x.u + 0x7fffu + ((x.u >> 16) & 1u);
  return (unsigned short)(r >> 16);
}
DEVI float bf2f(unsigned short h) {
  union { unsigned u; float f; } x; x.u = ((unsigned)h) << 16; return x.f;
}

DEVI void gload_lds16(const void* g, void* l) {
  __builtin_amdgcn_global_load_lds(
      (const __attribute__((address_space(1))) unsigned int*)g,
      (__attribute__((address_space(3))) unsigned int*)l, 16, 0, 0);
}

// ---------- kernel: out = x + pos_embed ----------
__global__ void k_addpos(const float* __restrict__ x, const float* __restrict__ pos,
                         float* __restrict__ out) {
  int i = blockIdx.x * 256 + threadIdx.x;
  const int NC4 = 1024 * 1024 / 4;
  f32x4 a = ((const f32x4*)x)[i];
  f32x4 p = ((const f32x4*)pos)[i & (NC4 - 1)];
  ((f32x4*)out)[i] = a + p;
}

// ---------- LayerNorm fp32 -> bf16, one wave per row (C=1024) ----------
__global__ __launch_bounds__(256) void k_ln(const float* __restrict__ in,
                                            const float* __restrict__ g,
                                            const float* __restrict__ b,
                                            unsigned short* __restrict__ out) {
  int wid = threadIdx.x >> 6, lane = threadIdx.x & 63;
  int row = blockIdx.x * 4 + wid;
  const float* r = in + (size_t)row * 1024;
  f32x4 v[4];
  float s = 0.f, s2 = 0.f;
#pragma unroll
  for (int j = 0; j < 4; j++) {
    v[j] = ((const f32x4*)r)[j * 64 + lane];
#pragma unroll
    for (int c = 0; c < 4; c++) { s += v[j][c]; s2 += v[j][c] * v[j][c]; }
  }
#pragma unroll
  for (int off = 32; off; off >>= 1) { s += __shfl_xor(s, off); s2 += __shfl_xor(s2, off); }
  float mean = s * (1.0f / 1024.0f);
  float var = s2 * (1.0f / 1024.0f) - mean * mean;
  float rstd = rsqrtf(var + 1e-5f);
  unsigned short* orow = out + (size_t)row * 1024;
#pragma unroll
  for (int j = 0; j < 4; j++) {
    f32x4 gv = ((const f32x4*)g)[j * 64 + lane];
    f32x4 bv = ((const f32x4*)b)[j * 64 + lane];
    float y0 = (v[j][0] - mean) * rstd * gv[0] + bv[0];
    float y1 = (v[j][1] - mean) * rstd * gv[1] + bv[1];
    float y2 = (v[j][2] - mean) * rstd * gv[2] + bv[2];
    float y3 = (v[j][3] - mean) * rstd * gv[3] + bv[3];
    uint2 w;
    w.x = (unsigned)f2bf(y0) | ((unsigned)f2bf(y1) << 16);
    w.y = (unsigned)f2bf(y2) | ((unsigned)f2bf(y3) << 16);
    *(uint2*)(orow + (j * 64 + lane) * 4) = w;
  }
}

// ---------- transpose-convert: W[K,N] fp32 -> Wt[N,K] bf16 ----------
__global__ __launch_bounds__(256) void k_wconv(const float* __restrict__ W,
                                               unsigned short* __restrict__ Wt,
                                               int K, int N) {
  __shared__ float t[32][33];
  const int bk = blockIdx.y * 32, bn = blockIdx.x * 32;
  const int a = threadIdx.x >> 3, b4 = (threadIdx.x & 7) * 4;
  f32x4 v = *(const f32x4*)(W + (size_t)(bk + a) * N + bn + b4);
  t[a][b4 + 0] = v[0]; t[a][b4 + 1] = v[1]; t[a][b4 + 2] = v[2]; t[a][b4 + 3] = v[3];
  __syncthreads();
  uint2 w;
  w.x = (unsigned)f2bf(t[b4 + 0][a]) | ((unsigned)f2bf(t[b4 + 1][a]) << 16);
  w.y = (unsigned)f2bf(t[b4 + 2][a]) | ((unsigned)f2bf(t[b4 + 3][a]) << 16);
  *(uint2*)(Wt + (size_t)(bn + a) * K + bk + b4) = w;
}

// ---------- GEMM (m97 structure): C = A[M,K](bf16) @ Wt[N,K](bf16)^T ----------
// EPI 0: QKV split-write (q scaled 1/8) to [3][B*H, N, 64] bf16
// EPI 1: atomicAdd residual fp32 (proj)
// EPI 2: exact GELU -> bf16 (fc1)
// EPI 3: atomicAdd residual fp32 (fc2)
template <int EPI>
__global__ __launch_bounds__(256, 3) void k_gemm(const unsigned short* __restrict__ A,
                                                 const unsigned short* __restrict__ Bt,
                                                 const float* __restrict__ bias,
                                                 unsigned short* __restrict__ outb,
                                                 float* __restrict__ outf,
                                                 int Kfull, int KC, int Nout) {
  __shared__ unsigned short As[2][128 * 32];
  __shared__ unsigned short Bs[2][128 * 32];
  const int tid = threadIdx.x, wid = tid >> 6, lane = tid & 63;
  const int r16 = lane & 15, gq = lane >> 4;

  // XCD-aware bijective swizzle (all grids have nwg % 8 == 0)
  const int gx = gridDim.x, nwg = gx * gridDim.y;
  const int f = blockIdx.y * gx + blockIdx.x;
  const int cpx = nwg >> 3;
  const int s = (f & 7) * cpx + (f >> 3);
  const int bn = s % gx, bm = s / gx;

  const int row0g = bm * 128, col0g = bn * 128;
  const int k0 = blockIdx.z * KC;

  const int ci0 = wid * 64 + lane;           // chunk index, p adds 256
  auto stage = [&](int buf, int t) {
#pragma unroll
    for (int p = 0; p < 2; p++) {
      int ci = p * 256 + ci0;
      const unsigned short* srcA = A + (size_t)(row0g + (ci >> 2)) * Kfull + k0 + t * 32 + (ci & 3) * 8;
      gload_lds16(srcA, &As[buf][(p * 256 + wid * 64) * 8]);
      const unsigned short* srcB = Bt + (size_t)(col0g + (ci >> 2)) * Kfull + k0 + t * 32 + (ci & 3) * 8;
      gload_lds16(srcB, &Bs[buf][(p * 256 + wid * 64) * 8]);
    }
  };

  f32x4 acc[4][4] = {};
  const int NT = KC >> 5;
  const int a_base = (wid >> 1) * 64, b_base = (wid & 1) * 64;

  stage(0, 0);
  int cur = 0;
  for (int t = 0; t < NT; t++) {
    __syncthreads();                       // drains vmcnt -> buf[cur] ready
    if (t + 1 < NT) stage(cur ^ 1, t + 1);
    bf16x8 af[4], bfr[4];
#pragma unroll
    for (int im = 0; im < 4; im++)
      af[im] = *(const bf16x8*)&As[cur][(a_base + im * 16 + r16) * 32 + gq * 8];
#pragma unroll
    for (int in = 0; in < 4; in++)
      bfr[in] = *(const bf16x8*)&Bs[cur][(b_base + in * 16 + r16) * 32 + gq * 8];
#pragma unroll
    for (int im = 0; im < 4; im++)
#pragma unroll
      for (int in = 0; in < 4; in++)
        acc[im][in] = __builtin_amdgcn_mfma_f32_16x16x32_bf16(af[im], bfr[in], acc[im][in], 0, 0, 0);
    cur ^= 1;
  }

  const int row0 = row0g + a_base, col0 = col0g + b_base;
  const bool bz = (blockIdx.z == 0);
#pragma unroll
  for (int in = 0; in < 4; in++) {
    int c = col0 + in * 16 + r16;
    float bv = bz ? bias[c] : 0.f;
#pragma unroll
    for (int im = 0; im < 4; im++) {
      int rb = row0 + im * 16 + gq * 4;
#pragma unroll
      for (int jr = 0; jr < 4; jr++) {
        float val = acc[im][in][jr] + bv;
        int r = rb + jr;
        if (EPI == 0) {
          int part = c >> 10, cc = c & 1023;
          int hh = cc >> 6, d = cc & 63;
          int bb = r >> 10, n = r & 1023;
          if (part == 0) val *= 0.125f;  // SCALE = 64^-0.5
          outb[(size_t)part * 4194304 + ((size_t)(bb * 16 + hh) * 1024 + n) * 64 + d] = f2bf(val);
        } else if (EPI == 2) {
          float gx2 = 0.5f * val * (1.0f + erff(val * 0.70710678118f));
          outb[(size_t)r * 4096 + c] = f2bf(gx2);
        } else {
          atomicAdd(outf + (size_t)r * 1024 + c, val);
        }
      }
    }
  }
}

// ---------- attention: scores + row max/argmax/sum-exp + threshold gather ----------
__global__ __launch_bounds__(256) void k_attn(const unsigned short* __restrict__ q,
                                              const unsigned short* __restrict__ k,
                                              const unsigned short* __restrict__ v,
                                              unsigned short* __restrict__ ao) {
  const int wid = threadIdx.x >> 6, lane = threadIdx.x & 63;
  const int r16 = lane & 15, g = lane >> 4;
  const int bh = blockIdx.x >> 4, qt = blockIdx.x & 15;
  const int b = bh >> 4, h = bh & 15;
  const unsigned short* qb = q + (size_t)bh * 1024 * 64;
  const unsigned short* kb = k + (size_t)bh * 1024 * 64;
  const unsigned short* vb = v + (size_t)bh * 1024 * 64;
  const int n_base = qt * 64 + wid * 16;

  bf16x8 qf0 = *(const bf16x8*)(qb + (size_t)(n_base + r16) * 64 + g * 8);
  bf16x8 qf1 = *(const bf16x8*)(qb + (size_t)(n_base + r16) * 64 + 32 + g * 8);

  float gsum[4] = {0.f, 0.f, 0.f, 0.f};
  float gmax[4] = {-3e38f, -3e38f, -3e38f, -3e38f};
  int gidx[4] = {0, 0, 0, 0};

  for (int mt = 0; mt < 64; mt++) {
    int m0 = mt * 16;
    bf16x8 kf0 = *(const bf16x8*)(kb + (size_t)(m0 + r16) * 64 + g * 8);
    bf16x8 kf1 = *(const bf16x8*)(kb + (size_t)(m0 + r16) * 64 + 32 + g * 8);
    f32x4 s = {0.f, 0.f, 0.f, 0.f};
    s = __builtin_amdgcn_mfma_f32_16x16x32_bf16(qf0, kf0, s, 0, 0, 0);
    s = __builtin_amdgcn_mfma_f32_16x16x32_bf16(qf1, kf1, s, 0, 0, 0);
#pragma unroll
    for (int jr = 0; jr < 4; jr++) {
      float sc = s[jr];
      float e = __expf(sc);
#pragma unroll
      for (int off = 1; off < 16; off <<= 1) e += __shfl_xor(e, off);
      float mv = sc; int mi = m0 + r16;
#pragma unroll
      for (int off = 1; off < 16; off <<= 1) {
        float ov = __shfl_xor(mv, off);
        int oi = __shfl_xor(mi, off);
        if (ov > mv) { mv = ov; mi = oi; }
      }
      gsum[jr] += e;
      if (mv > gmax[jr]) { gmax[jr] = mv; gidx[jr] = mi; }
    }
  }

#pragma unroll
  for (int jr = 0; jr < 4; jr++) {
    int n = n_base + g * 4 + jr;
    float wgt = __expf(gmax[jr]) / gsum[jr];
    uint2 w; w.x = 0u; w.y = 0u;
    if (wgt > 0.5f) {
      uint2 raw = *(const uint2*)(vb + (size_t)gidx[jr] * 64 + r16 * 4);
      unsigned short a0 = raw.x & 0xffff, a1 = raw.x >> 16;
      unsigned short a2 = raw.y & 0xffff, a3 = raw.y >> 16;
      w.x = (unsigned)f2bf(wgt * bf2f(a0)) | ((unsigned)f2bf(wgt * bf2f(a1)) << 16);
      w.y = (unsigned)f2bf(wgt * bf2f(a2)) | ((unsigned)f2bf(wgt * bf2f(a3)) << 16);
    }
    *(uint2*)(ao + ((size_t)b * 1024 + n) * 1024 + h * 64 + r16 * 4) = w;
  }
}

// ---------- launcher ----------
extern "C" void kernel_launch(void* const* d_in, const int* in_sizes, int n_in,
                              void* d_out, int out_size, void* d_ws, size_t ws_size,
                              hipStream_t stream) {
  const float* x      = (const float*)d_in[0];
  const float* pos    = (const float*)d_in[1];
  const float* qkv_w  = (const float*)d_in[2];
  const float* qkv_b  = (const float*)d_in[3];
  const float* proj_w = (const float*)d_in[4];
  const float* proj_b = (const float*)d_in[5];
  const float* ln1_g  = (const float*)d_in[6];
  const float* ln1_b  = (const float*)d_in[7];
  const float* ln2_g  = (const float*)d_in[8];
  const float* ln2_b  = (const float*)d_in[9];
  const float* fc1_w  = (const float*)d_in[10];
  const float* fc1_b  = (const float*)d_in[11];
  const float* fc2_w  = (const float*)d_in[12];
  const float* fc2_b  = (const float*)d_in[13];
  float* out = (float*)d_out;

  char* ws = (char*)d_ws;
  unsigned short* xh  = (unsigned short*)ws;                 // 0..8MB   LN out / attn out
  unsigned short* qkv = (unsigned short*)(ws + (8u << 20));  // 8..32MB  q,k,v (attn phase)
  unsigned short* m1  = (unsigned short*)(ws + (8u << 20));  // 8..40MB  gelu out (mlp phase)
  unsigned short* wt  = (unsigned short*)(ws + (40u << 20)); // 40..48MB weight bf16 [N,K]

  k_addpos<<<4096, 256, 0, stream>>>(x, pos, out);
  for (int l = 0; l < 4; l++) {
    k_ln<<<1024, 256, 0, stream>>>(out, ln1_g + l * 1024, ln1_b + l * 1024, xh);

    k_wconv<<<dim3(96, 32), 256, 0, stream>>>(qkv_w + (size_t)l * 1024 * 3072, wt, 1024, 3072);
    k_gemm<0><<<dim3(24, 32, 1), 256, 0, stream>>>(xh, wt, qkv_b + l * 3072, qkv, nullptr,
                                                   1024, 1024, 3072);
    k_attn<<<1024, 256, 0, stream>>>(qkv, qkv + 4194304, qkv + 2 * 4194304, xh);

    k_wconv<<<dim3(32, 32), 256, 0, stream>>>(proj_w + (size_t)l * 1024 * 1024, wt, 1024, 1024);
    k_gemm<1><<<dim3(8, 32, 2), 256, 0, stream>>>(xh, wt, proj_b + l * 1024, nullptr, out,
                                                  1024, 512, 1024);

    k_ln<<<1024, 256, 0, stream>>>(out, ln2_g + l * 1024, ln2_b + l * 1024, xh);

    k_wconv<<<dim3(128, 32), 256, 0, stream>>>(fc1_w + (size_t)l * 1024 * 4096, wt, 1024, 4096);
    k_gemm<2><<<dim3(32, 32, 1), 256, 0, stream>>>(xh, wt, fc1_b + l * 4096, m1, nullptr,
                                                   1024, 1024, 4096);

    k_wconv<<<dim3(32, 128), 256, 0, stream>>>(fc2_w + (size_t)l * 4096 * 1024, wt, 4096, 1024);
    k_gemm<3><<<dim3(8, 32, 4), 256, 0, stream>>>(m1, wt, fc2_b + l * 1024, nullptr, out,
                                                  4096, 1024, 1024);
  }
}

// Round 4
// 1419.095 us; speedup vs baseline: 1.6702x; 1.1908x over previous
//
#include <hip/hip_runtime.h>
#include <stdint.h>

#define DEVI __device__ __forceinline__

typedef __attribute__((ext_vector_type(4))) float f32x4;
typedef __attribute__((ext_vector_type(8))) __bf16 bf16x8;

// ---------- bf16 helpers (RNE) ----------
DEVI unsigned short f2bf(float f) {
  union { float f; unsigned u; } x; x.f = f;
  unsigned r = x.u + 0x7fffu + ((x.u >> 16) & 1u);
  return (unsigned short)(r >> 16);
}
DEVI float bf2f(unsigned short h) {
  union { unsigned u; float f; } x; x.u = ((unsigned)h) << 16; return x.f;
}

DEVI void gload_lds16(const void* g, void* l) {
  __builtin_amdgcn_global_load_lds(
      (const __attribute__((address_space(1))) unsigned int*)g,
      (__attribute__((address_space(3))) unsigned int*)l, 16, 0, 0);
}

// ---------- kernel: out = x + pos_embed ----------
__global__ void k_addpos(const float* __restrict__ x, const float* __restrict__ pos,
                         float* __restrict__ out) {
  int i = blockIdx.x * 256 + threadIdx.x;
  const int NC4 = 1024 * 1024 / 4;
  f32x4 a = ((const f32x4*)x)[i];
  f32x4 p = ((const f32x4*)pos)[i & (NC4 - 1)];
  ((f32x4*)out)[i] = a + p;
}

// ---------- LayerNorm fp32 -> bf16, one wave per row (C=1024) ----------
__global__ __launch_bounds__(256) void k_ln(const float* __restrict__ in,
                                            const float* __restrict__ g,
                                            const float* __restrict__ b,
                                            unsigned short* __restrict__ out) {
  int wid = threadIdx.x >> 6, lane = threadIdx.x & 63;
  int row = blockIdx.x * 4 + wid;
  const float* r = in + (size_t)row * 1024;
  f32x4 v[4];
  float s = 0.f, s2 = 0.f;
#pragma unroll
  for (int j = 0; j < 4; j++) {
    v[j] = ((const f32x4*)r)[j * 64 + lane];
#pragma unroll
    for (int c = 0; c < 4; c++) { s += v[j][c]; s2 += v[j][c] * v[j][c]; }
  }
#pragma unroll
  for (int off = 32; off; off >>= 1) { s += __shfl_xor(s, off); s2 += __shfl_xor(s2, off); }
  float mean = s * (1.0f / 1024.0f);
  float var = s2 * (1.0f / 1024.0f) - mean * mean;
  float rstd = rsqrtf(var + 1e-5f);
  unsigned short* orow = out + (size_t)row * 1024;
#pragma unroll
  for (int j = 0; j < 4; j++) {
    f32x4 gv = ((const f32x4*)g)[j * 64 + lane];
    f32x4 bv = ((const f32x4*)b)[j * 64 + lane];
    float y0 = (v[j][0] - mean) * rstd * gv[0] + bv[0];
    float y1 = (v[j][1] - mean) * rstd * gv[1] + bv[1];
    float y2 = (v[j][2] - mean) * rstd * gv[2] + bv[2];
    float y3 = (v[j][3] - mean) * rstd * gv[3] + bv[3];
    uint2 w;
    w.x = (unsigned)f2bf(y0) | ((unsigned)f2bf(y1) << 16);
    w.y = (unsigned)f2bf(y2) | ((unsigned)f2bf(y3) << 16);
    *(uint2*)(orow + (j * 64 + lane) * 4) = w;
  }
}

// ---------- transpose-convert: W[K,N] fp32 -> Wt[N,K] bf16 ----------
__global__ __launch_bounds__(256) void k_wconv(const float* __restrict__ W,
                                               unsigned short* __restrict__ Wt,
                                               int K, int N) {
  __shared__ float t[32][33];
  const int bk = blockIdx.y * 32, bn = blockIdx.x * 32;
  const int a = threadIdx.x >> 3, b4 = (threadIdx.x & 7) * 4;
  f32x4 v = *(const f32x4*)(W + (size_t)(bk + a) * N + bn + b4);
  t[a][b4 + 0] = v[0]; t[a][b4 + 1] = v[1]; t[a][b4 + 2] = v[2]; t[a][b4 + 3] = v[3];
  __syncthreads();
  uint2 w;
  w.x = (unsigned)f2bf(t[b4 + 0][a]) | ((unsigned)f2bf(t[b4 + 1][a]) << 16);
  w.y = (unsigned)f2bf(t[b4 + 2][a]) | ((unsigned)f2bf(t[b4 + 3][a]) << 16);
  *(uint2*)(Wt + (size_t)(bn + a) * K + bk + b4) = w;
}

// ---------- GEMM (m97 structure): C = A[M,K](bf16) @ Wt[N,K](bf16)^T ----------
// EPI 0: QKV split-write (q scaled 1/8) to [3][B*H, N, 64] bf16
// EPI 1: atomicAdd residual fp32 (proj)
// EPI 2: exact GELU -> bf16 (fc1)
// EPI 3: atomicAdd residual fp32 (fc2)
template <int EPI>
__global__ __launch_bounds__(256, 3) void k_gemm(const unsigned short* __restrict__ A,
                                                 const unsigned short* __restrict__ Bt,
                                                 const float* __restrict__ bias,
                                                 unsigned short* __restrict__ outb,
                                                 float* __restrict__ outf,
                                                 int Kfull, int KC, int Nout) {
  __shared__ unsigned short As[2][128 * 32];
  __shared__ unsigned short Bs[2][128 * 32];
  const int tid = threadIdx.x, wid = tid >> 6, lane = tid & 63;
  const int r16 = lane & 15, gq = lane >> 4;

  // XCD-aware bijective swizzle (all grids have nwg % 8 == 0)
  const int gx = gridDim.x, nwg = gx * gridDim.y;
  const int f = blockIdx.y * gx + blockIdx.x;
  const int cpx = nwg >> 3;
  const int s = (f & 7) * cpx + (f >> 3);
  const int bn = s % gx, bm = s / gx;

  const int row0g = bm * 128, col0g = bn * 128;
  const int k0 = blockIdx.z * KC;

  const int ci0 = wid * 64 + lane;           // chunk index, p adds 256
  auto stage = [&](int buf, int t) {
#pragma unroll
    for (int p = 0; p < 2; p++) {
      int ci = p * 256 + ci0;
      const unsigned short* srcA = A + (size_t)(row0g + (ci >> 2)) * Kfull + k0 + t * 32 + (ci & 3) * 8;
      gload_lds16(srcA, &As[buf][(p * 256 + wid * 64) * 8]);
      const unsigned short* srcB = Bt + (size_t)(col0g + (ci >> 2)) * Kfull + k0 + t * 32 + (ci & 3) * 8;
      gload_lds16(srcB, &Bs[buf][(p * 256 + wid * 64) * 8]);
    }
  };

  f32x4 acc[4][4] = {};
  const int NT = KC >> 5;
  const int a_base = (wid >> 1) * 64, b_base = (wid & 1) * 64;

  stage(0, 0);
  int cur = 0;
  for (int t = 0; t < NT; t++) {
    __syncthreads();                       // drains vmcnt -> buf[cur] ready
    if (t + 1 < NT) stage(cur ^ 1, t + 1);
    bf16x8 af[4], bfr[4];
#pragma unroll
    for (int im = 0; im < 4; im++)
      af[im] = *(const bf16x8*)&As[cur][(a_base + im * 16 + r16) * 32 + gq * 8];
#pragma unroll
    for (int in = 0; in < 4; in++)
      bfr[in] = *(const bf16x8*)&Bs[cur][(b_base + in * 16 + r16) * 32 + gq * 8];
#pragma unroll
    for (int im = 0; im < 4; im++)
#pragma unroll
      for (int in = 0; in < 4; in++)
        acc[im][in] = __builtin_amdgcn_mfma_f32_16x16x32_bf16(af[im], bfr[in], acc[im][in], 0, 0, 0);
    cur ^= 1;
  }

  const int row0 = row0g + a_base, col0 = col0g + b_base;
  const bool bz = (blockIdx.z == 0);
#pragma unroll
  for (int in = 0; in < 4; in++) {
    int c = col0 + in * 16 + r16;
    float bv = bz ? bias[c] : 0.f;
#pragma unroll
    for (int im = 0; im < 4; im++) {
      int rb = row0 + im * 16 + gq * 4;
#pragma unroll
      for (int jr = 0; jr < 4; jr++) {
        float val = acc[im][in][jr] + bv;
        int r = rb + jr;
        if (EPI == 0) {
          int part = c >> 10, cc = c & 1023;
          int hh = cc >> 6, d = cc & 63;
          int bb = r >> 10, n = r & 1023;
          if (part == 0) val *= 0.125f;  // SCALE = 64^-0.5
          outb[(size_t)part * 4194304 + ((size_t)(bb * 16 + hh) * 1024 + n) * 64 + d] = f2bf(val);
        } else if (EPI == 2) {
          float gx2 = 0.5f * val * (1.0f + erff(val * 0.70710678118f));
          outb[(size_t)r * 4096 + c] = f2bf(gx2);
        } else {
          atomicAdd(outf + (size_t)r * 1024 + c, val);
        }
      }
    }
  }
}

// ---------- attention: per-lane accumulate of max/argmax/sum-exp, reduce once ----------
// Lane (g,r16) holds score of query (n_base + g*4 + jr) vs key (m0 + r16).
__global__ __launch_bounds__(256) void k_attn(const unsigned short* __restrict__ q,
                                              const unsigned short* __restrict__ k,
                                              const unsigned short* __restrict__ v,
                                              unsigned short* __restrict__ ao) {
  const int wid = threadIdx.x >> 6, lane = threadIdx.x & 63;
  const int r16 = lane & 15, g = lane >> 4;
  const int bh = blockIdx.x >> 4, qt = blockIdx.x & 15;
  const int b = bh >> 4, h = bh & 15;
  const unsigned short* qb = q + (size_t)bh * 1024 * 64;
  const unsigned short* kb = k + (size_t)bh * 1024 * 64;
  const unsigned short* vb = v + (size_t)bh * 1024 * 64;
  const int n_base = qt * 64 + wid * 16;

  bf16x8 qf0 = *(const bf16x8*)(qb + (size_t)(n_base + r16) * 64 + g * 8);
  bf16x8 qf1 = *(const bf16x8*)(qb + (size_t)(n_base + r16) * 64 + 32 + g * 8);

  float esum[4] = {0.f, 0.f, 0.f, 0.f};
  float mv[4] = {-3e38f, -3e38f, -3e38f, -3e38f};
  int mi[4] = {0, 0, 0, 0};

#pragma unroll 2
  for (int mt = 0; mt < 64; mt++) {
    int m0 = mt * 16;
    bf16x8 kf0 = *(const bf16x8*)(kb + (size_t)(m0 + r16) * 64 + g * 8);
    bf16x8 kf1 = *(const bf16x8*)(kb + (size_t)(m0 + r16) * 64 + 32 + g * 8);
    f32x4 s = {0.f, 0.f, 0.f, 0.f};
    s = __builtin_amdgcn_mfma_f32_16x16x32_bf16(qf0, kf0, s, 0, 0, 0);
    s = __builtin_amdgcn_mfma_f32_16x16x32_bf16(qf1, kf1, s, 0, 0, 0);
#pragma unroll
    for (int jr = 0; jr < 4; jr++) {
      float sc = s[jr];
      esum[jr] += __expf(sc);
      if (sc > mv[jr]) { mv[jr] = sc; mi[jr] = m0 + r16; }
    }
  }

  // one final reduction across the 16 lanes sharing g (key slots)
#pragma unroll
  for (int jr = 0; jr < 4; jr++) {
#pragma unroll
    for (int off = 1; off < 16; off <<= 1) {
      esum[jr] += __shfl_xor(esum[jr], off);
      float ov = __shfl_xor(mv[jr], off);
      int oi = __shfl_xor(mi[jr], off);
      if (ov > mv[jr]) { mv[jr] = ov; mi[jr] = oi; }
    }
  }

#pragma unroll
  for (int jr = 0; jr < 4; jr++) {
    int n = n_base + g * 4 + jr;
    float wgt = __expf(mv[jr]) / esum[jr];
    uint2 w; w.x = 0u; w.y = 0u;
    if (wgt > 0.5f) {
      uint2 raw = *(const uint2*)(vb + (size_t)mi[jr] * 64 + r16 * 4);
      unsigned short a0 = raw.x & 0xffff, a1 = raw.x >> 16;
      unsigned short a2 = raw.y & 0xffff, a3 = raw.y >> 16;
      w.x = (unsigned)f2bf(wgt * bf2f(a0)) | ((unsigned)f2bf(wgt * bf2f(a1)) << 16);
      w.y = (unsigned)f2bf(wgt * bf2f(a2)) | ((unsigned)f2bf(wgt * bf2f(a3)) << 16);
    }
    *(uint2*)(ao + ((size_t)b * 1024 + n) * 1024 + h * 64 + r16 * 4) = w;
  }
}

// ---------- launcher ----------
extern "C" void kernel_launch(void* const* d_in, const int* in_sizes, int n_in,
                              void* d_out, int out_size, void* d_ws, size_t ws_size,
                              hipStream_t stream) {
  const float* x      = (const float*)d_in[0];
  const float* pos    = (const float*)d_in[1];
  const float* qkv_w  = (const float*)d_in[2];
  const float* qkv_b  = (const float*)d_in[3];
  const float* proj_w = (const float*)d_in[4];
  const float* proj_b = (const float*)d_in[5];
  const float* ln1_g  = (const float*)d_in[6];
  const float* ln1_b  = (const float*)d_in[7];
  const float* ln2_g  = (const float*)d_in[8];
  const float* ln2_b  = (const float*)d_in[9];
  const float* fc1_w  = (const float*)d_in[10];
  const float* fc1_b  = (const float*)d_in[11];
  const float* fc2_w  = (const float*)d_in[12];
  const float* fc2_b  = (const float*)d_in[13];
  float* out = (float*)d_out;

  char* ws = (char*)d_ws;
  unsigned short* xh  = (unsigned short*)ws;                 // 0..8MB   LN out / attn out
  unsigned short* qkv = (unsigned short*)(ws + (8u << 20));  // 8..32MB  q,k,v (attn phase)
  unsigned short* m1  = (unsigned short*)(ws + (8u << 20));  // 8..40MB  gelu out (mlp phase)
  unsigned short* wt  = (unsigned short*)(ws + (40u << 20)); // 40..48MB weight bf16 [N,K]

  k_addpos<<<4096, 256, 0, stream>>>(x, pos, out);
  for (int l = 0; l < 4; l++) {
    k_ln<<<1024, 256, 0, stream>>>(out, ln1_g + l * 1024, ln1_b + l * 1024, xh);

    k_wconv<<<dim3(96, 32), 256, 0, stream>>>(qkv_w + (size_t)l * 1024 * 3072, wt, 1024, 3072);
    k_gemm<0><<<dim3(24, 32, 1), 256, 0, stream>>>(xh, wt, qkv_b + l * 3072, qkv, nullptr,
                                                   1024, 1024, 3072);
    k_attn<<<1024, 256, 0, stream>>>(qkv, qkv + 4194304, qkv + 2 * 4194304, xh);

    k_wconv<<<dim3(32, 32), 256, 0, stream>>>(proj_w + (size_t)l * 1024 * 1024, wt, 1024, 1024);
    k_gemm<1><<<dim3(8, 32, 2), 256, 0, stream>>>(xh, wt, proj_b + l * 1024, nullptr, out,
                                                  1024, 512, 1024);

    k_ln<<<1024, 256, 0, stream>>>(out, ln2_g + l * 1024, ln2_b + l * 1024, xh);

    k_wconv<<<dim3(128, 32), 256, 0, stream>>>(fc1_w + (size_t)l * 1024 * 4096, wt, 1024, 4096);
    k_gemm<2><<<dim3(32, 32, 1), 256, 0, stream>>>(xh, wt, fc1_b + l * 4096, m1, nullptr,
                                                   1024, 1024, 4096);

    k_wconv<<<dim3(32, 128), 256, 0, stream>>>(fc2_w + (size_t)l * 4096 * 1024, wt, 4096, 1024);
    k_gemm<3><<<dim3(8, 32, 4), 256, 0, stream>>>(m1, wt, fc2_b + l * 1024, nullptr, out,
                                                  4096, 1024, 1024);
  }
}